// Round 1
// 3299.594 us; speedup vs baseline: 1.7257x; 1.7257x over previous
//
#include <hip/hip_runtime.h>
#include <hip/hip_bf16.h>
#include <cstdint>
#include <cstddef>

#define B_   64
#define CIN  1024
#define L_   1024
#define T_   64
#define Hh_  256
#define Dd_  256
#define Cc_  111
#define NO_  512
#define KX_  623

typedef __attribute__((ext_vector_type(8))) short short8;
typedef __attribute__((ext_vector_type(4))) float floatx4;

__device__ __forceinline__ float bf2f(unsigned short u) {
    union { unsigned int i; float f; } v; v.i = ((unsigned int)u) << 16; return v.f;
}
__device__ __forceinline__ unsigned short f2bf(float f) {
    union { float f; unsigned int i; } v; v.f = f;
    return (unsigned short)((v.i + 0x7fffu + ((v.i >> 16) & 1u)) >> 16);
}
__device__ __forceinline__ float frcp(float x) { return __builtin_amdgcn_rcpf(x); }
__device__ __forceinline__ float tanh_fast(float x) {
    return 1.0f - 2.0f * frcp(1.0f + __expf(2.0f * x));
}
__device__ __forceinline__ float sig_fast(float x) {
    return frcp(1.0f + __expf(-x));
}

// ---------------- prep kernels ----------------

__global__ void pe_kernel(float* __restrict__ PE) {
    int idx = blockIdx.x * 256 + threadIdx.x;
    if (idx >= L_ * NO_) return;
    int l = idx >> 9, j = idx & 511;
    int i2 = j & ~1;
    float div = expf((float)i2 * (-9.210340371976184f / 512.0f));
    float arg = (float)l * div;
    PE[idx] = (j & 1) ? cosf(arg) : sinf(arg);
}

__global__ void wc_kernel(const float* __restrict__ conv_w,
                          const float* __restrict__ attn_w,
                          unsigned short* __restrict__ Wc) {
    int c = blockIdx.x * 256 + threadIdx.x;
    int o = blockIdx.y;
    float v;
    if (o < 256) {
        v = conv_w[(size_t)o * CIN + c];
    } else {
        const float* aw = attn_w + (size_t)(o - 256) * 512;
        float a = 0.0f;
        for (int d = 0; d < 512; ++d)
            a = fmaf(aw[d], conv_w[(size_t)d * CIN + c], a);
        v = a;
    }
    Wc[(size_t)o * CIN + c] = f2bf(v);
}

__global__ void biasf_kernel(const float* __restrict__ conv_b,
                             const float* __restrict__ PE,
                             float* __restrict__ biasC) {
    int idx = blockIdx.x * 256 + threadIdx.x;
    int l = idx >> 8, j = idx & 255;
    biasC[(size_t)l * NO_ + j] = conv_b[j] + PE[(size_t)l * NO_ + j];
}

__global__ void biasw_kernel(const float* __restrict__ conv_b,
                             const float* __restrict__ PE,
                             const float* __restrict__ attn_w,
                             const float* __restrict__ attn_b,
                             float* __restrict__ biasC) {
    int l = blockIdx.x * 256 + threadIdx.x;
    int h = blockIdx.y;
    const float* aw = attn_w + (size_t)h * 512;
    const float* pe = PE + (size_t)l * NO_;
    float a = 0.0f;
    for (int d = 0; d < 512; ++d)
        a = fmaf(aw[d], conv_b[d] + pe[d], a);
    biasC[(size_t)l * NO_ + 256 + h] = a + attn_b[h];
}

__global__ void wiht_kernel(const float* __restrict__ wih, unsigned short* __restrict__ WihT) {
    int idx = blockIdx.x * 256 + threadIdx.x;
    if (idx >= 768 * KX_) return;
    int o = idx / KX_, k = idx - o * KX_;
    WihT[(size_t)k * 768 + o] = f2bf(wih[idx]);
}
__global__ void whht_kernel(const float* __restrict__ whh, unsigned short* __restrict__ WhhT) {
    int idx = blockIdx.x * 256 + threadIdx.x;
    if (idx >= 768 * 256) return;
    int o = idx >> 8, k = idx & 255;
    WhhT[(size_t)k * 768 + o] = f2bf(whh[idx]);
}
__global__ void woutt_kernel(const float* __restrict__ outw, unsigned short* __restrict__ WoutT) {
    int idx = blockIdx.x * 256 + threadIdx.x;
    if (idx >= Cc_ * KX_) return;
    int c = idx / KX_, k = idx - c * KX_;
    WoutT[(size_t)k * 128 + c] = f2bf(outw[idx]);
}

__global__ void zero_kernel(int* __restrict__ p, int n) {
    int i = blockIdx.x * 256 + threadIdx.x;
    if (i < n) p[i] = 0;
}

// ---------------- fused conv+projection GEMM (unchanged) ----------------
__global__ __launch_bounds__(256) void gemm_feats(
    const float* __restrict__ fm,
    const unsigned short* __restrict__ Wc,
    const float* __restrict__ biasC,
    unsigned short* __restrict__ F) {
    __shared__ __align__(16) unsigned short Als[128 * 40];
    __shared__ __align__(16) unsigned short Bls[128 * 40];
    const int tid  = threadIdx.x;
    const int bx   = blockIdx.x;
    const int bb   = bx >> 3;
    const int l0   = (bx & 7) << 7;
    const int n0   = blockIdx.y << 7;
    const int wid  = tid >> 6;
    const int lane = tid & 63;
    const int m0w  = (wid & 1) << 6;
    const int n0w  = (wid >> 1) << 6;
    const int quad = lane >> 4;
    const int l16  = lane & 15;

    floatx4 acc[4][4];
#pragma unroll
    for (int i = 0; i < 4; ++i)
#pragma unroll
        for (int j = 0; j < 4; ++j)
            acc[i][j] = (floatx4){0.f, 0.f, 0.f, 0.f};

    const int lt    = tid & 127;
    const int chalf = tid >> 7;
    const float* fmb = fm + ((size_t)bb * CIN) * L_ + l0 + lt;
    const int bo = tid >> 2;
    const int bc = (tid & 3) << 3;
    const int swzA = ((lt >> 2) & 3) << 3;

    for (int kk = 0; kk < 32; ++kk) {
        const int c0 = kk << 5;
        __syncthreads();
#pragma unroll
        for (int i = 0; i < 8; ++i) {
            int cc = (chalf + (i << 1)) << 1;
            float v0 = fmb[(size_t)(c0 + cc) * L_];
            float v1 = fmb[(size_t)(c0 + cc + 1) * L_];
            unsigned int pk = (unsigned int)f2bf(v0) | ((unsigned int)f2bf(v1) << 16);
            *(unsigned int*)(&Als[lt * 40 + (cc ^ swzA)]) = pk;
        }
#pragma unroll
        for (int i = 0; i < 2; ++i) {
            int o = bo + (i << 6);
            uint4 w = *(const uint4*)(&Wc[(size_t)(n0 + o) * CIN + c0 + bc]);
            *(uint4*)(&Bls[o * 40 + bc]) = w;
        }
        __syncthreads();
        short8 afr[4], bfr[4];
#pragma unroll
        for (int mf = 0; mf < 4; ++mf) {
            int mm = m0w + (mf << 4) + l16;
            int k0 = (quad << 3) ^ (((mm >> 2) & 3) << 3);
            afr[mf] = *(const short8*)(&Als[mm * 40 + k0]);
        }
#pragma unroll
        for (int nf = 0; nf < 4; ++nf) {
            int nn = n0w + (nf << 4) + l16;
            bfr[nf] = *(const short8*)(&Bls[nn * 40 + (quad << 3)]);
        }
#pragma unroll
        for (int mf = 0; mf < 4; ++mf)
#pragma unroll
            for (int nf = 0; nf < 4; ++nf)
                acc[mf][nf] = __builtin_amdgcn_mfma_f32_16x16x32_bf16(afr[mf], bfr[nf], acc[mf][nf], 0, 0, 0);
    }

#pragma unroll
    for (int mf = 0; mf < 4; ++mf) {
#pragma unroll
        for (int nf = 0; nf < 4; ++nf) {
            int colg = n0 + n0w + (nf << 4) + l16;
#pragma unroll
            for (int r = 0; r < 4; ++r) {
                int lb = l0 + m0w + (mf << 4) + (quad << 2) + r;
                float v = acc[mf][nf][r] + biasC[(size_t)lb * NO_ + colg];
                F[((size_t)bb * L_ + lb) * NO_ + colg] = f2bf(v);
            }
        }
    }
}

// ---------------- decoder: 4 blocks per batch, per-batch global barrier ----------------

__device__ __forceinline__ void batch_barrier(int* bar, int target, int tid) {
    __syncthreads();
    if (tid == 0) {
        __hip_atomic_fetch_add(bar, 1, __ATOMIC_RELEASE, __HIP_MEMORY_SCOPE_AGENT);
        while (__hip_atomic_load(bar, __ATOMIC_ACQUIRE, __HIP_MEMORY_SCOPE_AGENT) < target) {
            __builtin_amdgcn_s_sleep(2);
        }
    }
    __syncthreads();
}

__global__ __launch_bounds__(1024, 4) void decoder_kernel(
    const unsigned short* __restrict__ F,
    const unsigned short* __restrict__ WihT,
    const unsigned short* __restrict__ WhhT,
    const unsigned short* __restrict__ WoutT,
    const float* __restrict__ cvv,
    const int* __restrict__ tgt,
    const float* __restrict__ emb,
    const float* __restrict__ bih,
    const float* __restrict__ bhh,
    const float* __restrict__ attn_v,
    const float* __restrict__ attn_vb,
    const float* __restrict__ cov_w,
    const float* __restrict__ cov_b,
    const float* __restrict__ outb,
    int* __restrict__ bar,
    float* __restrict__ gsum,
    float* __restrict__ gctx,
    float* __restrict__ ggih,
    float* __restrict__ OUT) {
    // Wf (attention half of F, cols 256..511 for this block's 256 l's) lives in
    // LDS for the whole decode: 256 x 256 bf16 = 128 KB. Loaded once.
    __shared__ __align__(16) unsigned short Wls[256 * 256];
    __shared__ float sc[256];     // e_l for this block's l-range
    __shared__ float cov[256];    // coverage for this block's l-range
    __shared__ float xv[640];     // [emb(256) | ctx(256) | cv(111)]
    __shared__ float xo[640];     // [h(256) | ctx(256) | cv(111)]
    __shared__ float hv[256];
    __shared__ __align__(16) float hbs[256];
    __shared__ __align__(16) float cwls[256];  // cov_w (was registers; freed for fctx)
    __shared__ __align__(16) float avls[256];  // attn_v
    __shared__ float gi[768];
    __shared__ float gh[768];
    __shared__ float ctxp[2048];
    __shared__ float outp[1024];
    __shared__ float red[32];

    const int tid  = threadIdx.x;
    const int bx   = blockIdx.x;
    const int b    = bx >> 2;
    const int sub  = bx & 3;
    const int l0   = sub << 8;
    const int lane = tid & 63;
    const int wid  = tid >> 6;
    const int l16  = tid & 15;
    const int lg   = tid >> 4;

    int* mybar = bar + b * 16;

    if (tid < 256) {
        cov[tid] = 0.0f; hv[tid] = 0.0f; hbs[tid] = cov_b[tid];
        cwls[tid] = cov_w[tid]; avls[tid] = attn_v[tid];
    }
    if (tid >= 512 && tid < 512 + Cc_) xv[tid] = cvv[b * Cc_ + (tid - 512)];

    const float avb = attn_vb[0];

    // ---- stage Wf (cols 256..511) into LDS: 8192 x 16B chunks, coalesced ----
#pragma unroll
    for (int i = 0; i < 8; ++i) {
        int c   = (i << 10) + tid;
        int row = c >> 5;
        int col = (c & 31) << 3;
        *(uint4*)(&Wls[(row << 8) + col]) =
            *(const uint4*)(F + (((size_t)(b * L_ + l0 + row)) << 9) + Hh_ + col);
    }

    // ---- stage ctx half (cols 0..255) into registers: 32 packed bf16x2 ----
    unsigned int fctx[32];
    {
        const int hp = (tid & 127) << 1;
        const int ch = tid >> 7;
        const unsigned short* fb = F + (((size_t)(b * L_ + l0 + (ch << 5))) << 9) + hp;
#pragma unroll
        for (int i = 0; i < 32; ++i)
            fctx[i] = *(const unsigned int*)(fb + ((size_t)i << 9));
    }

    const int cbase = sub * 28;
    const int ccnt  = (sub == 3) ? 27 : 28;
    const int kg0 = sub * 156;
    const int kg1 = (kg0 + 156 > KX_) ? KX_ : kg0 + 156;
    const int kh0 = sub << 6;

    int nsync = 0;
    __syncthreads();

    for (int t = 0; t < T_; ++t) {
        const int par = t & 1;
        float* myctx = gctx + (((size_t)b * 2 + par) * 4) * 256;
        float* mysum = gsum + ((size_t)b * 2 + par) * 4;
        float* mygg  = ggih + (((size_t)b * 2 + par) * 4) * 1536;

        // embedded token
        if (tid < 256) {
            int ytok = (t == 0) ? 1 : tgt[b * T_ + t - 1];
            xv[tid] = emb[ytok * Dd_ + tid];
        }

        // ---- attention scores for l in [l0, l0+256): 16 lanes per l ----
        // Wf now read from LDS (zero global traffic); cw/av/hb as float4 LDS reads.
#pragma unroll
        for (int pass = 0; pass < 4; ++pass) {
            int ll = (pass << 6) + lg;     // local l
            float covl = cov[ll];
            const unsigned short* wf = &Wls[ll << 8];
            float a = 0.0f;
#pragma unroll
            for (int j = 0; j < 4; ++j) {
                const int hb0 = (j << 6) + (l16 << 2);
                uint2 w = *(const uint2*)(wf + hb0);
                float4 cw4 = *(const float4*)(&cwls[hb0]);
                float4 av4 = *(const float4*)(&avls[hb0]);
                float4 hb4 = *(const float4*)(&hbs[hb0]);
                float g0 = bf2f((unsigned short)(w.x & 0xffffu)) + fmaf(covl, cw4.x, hb4.x);
                float g1 = bf2f((unsigned short)(w.x >> 16))     + fmaf(covl, cw4.y, hb4.y);
                float g2 = bf2f((unsigned short)(w.y & 0xffffu)) + fmaf(covl, cw4.z, hb4.z);
                float g3 = bf2f((unsigned short)(w.y >> 16))     + fmaf(covl, cw4.w, hb4.w);
                a = fmaf(av4.x, tanh_fast(g0), a);
                a = fmaf(av4.y, tanh_fast(g1), a);
                a = fmaf(av4.z, tanh_fast(g2), a);
                a = fmaf(av4.w, tanh_fast(g3), a);
            }
            a += __shfl_xor(a, 1);
            a += __shfl_xor(a, 2);
            a += __shfl_xor(a, 4);
            a += __shfl_xor(a, 8);
            if (l16 == 0) sc[ll] = __expf(a + avb);   // scores are O(1): no max-sub needed
        }
        __syncthreads();

        // ---- local exp-sum (256 values -> red[0..3]) ----
        if (tid < 256) {
            float e = sc[tid];
#pragma unroll
            for (int off = 1; off < 64; off <<= 1) e += __shfl_xor(e, off);
            if (lane == 0) red[wid] = e;
        }

        // ---- partial (unnormalized) context over local l-range: pure VALU now ----
        {
            int hp = (tid & 127) << 1;
            int ch = tid >> 7;
            float c0a = 0.0f, c1a = 0.0f;
#pragma unroll
            for (int i = 0; i < 32; ++i) {
                float al = sc[(ch << 5) + i];
                unsigned int w = fctx[i];
                c0a = fmaf(al, bf2f((unsigned short)(w & 0xffffu)), c0a);
                c1a = fmaf(al, bf2f((unsigned short)(w >> 16)), c1a);
            }
            ctxp[(ch << 8) + hp]     = c0a;
            ctxp[(ch << 8) + hp + 1] = c1a;
        }
        __syncthreads();

        // ---- publish partials ----
        if (tid < 256) {
            float s2 = 0.0f;
#pragma unroll
            for (int i = 0; i < 8; ++i) s2 += ctxp[(i << 8) + tid];
            __hip_atomic_store(&myctx[sub * 256 + tid], s2, __ATOMIC_RELAXED, __HIP_MEMORY_SCOPE_AGENT);
        } else if (tid == 256) {
            float ss = red[0] + red[1] + red[2] + red[3];
            __hip_atomic_store(&mysum[sub], ss, __ATOMIC_RELAXED, __HIP_MEMORY_SCOPE_AGENT);
        }

        ++nsync;
        batch_barrier(mybar, 4 * nsync, tid);

        // ---- assemble full context + 1/S ----
        float s2 = 0.0f;
        if (tid < 256) {
#pragma unroll
            for (int s = 0; s < 4; ++s)
                s2 += __hip_atomic_load(&myctx[s * 256 + tid], __ATOMIC_RELAXED, __HIP_MEMORY_SCOPE_AGENT);
        } else if (tid == 256) {
            float S = 0.0f;
#pragma unroll
            for (int s = 0; s < 4; ++s)
                S += __hip_atomic_load(&mysum[s], __ATOMIC_RELAXED, __HIP_MEMORY_SCOPE_AGENT);
            red[16] = frcp(S);
        }
        __syncthreads();
        float rS = red[16];
        if (tid < 256) {
            xv[256 + tid] = s2 * rS;
            cov[tid] += sc[tid] * rS;
        }
        __syncthreads();

        // ---- GRU partial matvecs (K-split 4-way) ----
        if (tid < 384) {
            int o = tid << 1;
            float a0 = 0.0f, a1 = 0.0f;
            const unsigned short* wp = WihT + o;
            for (int k = kg0; k < kg1; ++k) {
                float x = xv[k];
                unsigned int w = *(const unsigned int*)(wp + (size_t)k * 768);
                a0 = fmaf(x, bf2f((unsigned short)(w & 0xffffu)), a0);
                a1 = fmaf(x, bf2f((unsigned short)(w >> 16)), a1);
            }
            __hip_atomic_store(&mygg[sub * 1536 + o],     a0, __ATOMIC_RELAXED, __HIP_MEMORY_SCOPE_AGENT);
            __hip_atomic_store(&mygg[sub * 1536 + o + 1], a1, __ATOMIC_RELAXED, __HIP_MEMORY_SCOPE_AGENT);
        } else if (tid < 768) {
            int o = (tid - 384) << 1;
            float a0 = 0.0f, a1 = 0.0f;
            const unsigned short* wp = WhhT + o;
            for (int k = kh0; k < kh0 + 64; ++k) {
                float x = hv[k];
                unsigned int w = *(const unsigned int*)(wp + (size_t)k * 768);
                a0 = fmaf(x, bf2f((unsigned short)(w & 0xffffu)), a0);
                a1 = fmaf(x, bf2f((unsigned short)(w >> 16)), a1);
            }
            __hip_atomic_store(&mygg[sub * 1536 + 768 + o],     a0, __ATOMIC_RELAXED, __HIP_MEMORY_SCOPE_AGENT);
            __hip_atomic_store(&mygg[sub * 1536 + 768 + o + 1], a1, __ATOMIC_RELAXED, __HIP_MEMORY_SCOPE_AGENT);
        }

        ++nsync;
        batch_barrier(mybar, 4 * nsync, tid);

        // ---- reduce gi/gh (deterministic order -> identical h in all replicas) ----
        if (tid < 384) {
            int o = tid << 1;
            float v0 = bih[o], v1 = bih[o + 1];
#pragma unroll
            for (int s = 0; s < 4; ++s) {
                v0 += __hip_atomic_load(&mygg[s * 1536 + o],     __ATOMIC_RELAXED, __HIP_MEMORY_SCOPE_AGENT);
                v1 += __hip_atomic_load(&mygg[s * 1536 + o + 1], __ATOMIC_RELAXED, __HIP_MEMORY_SCOPE_AGENT);
            }
            gi[o] = v0; gi[o + 1] = v1;
        } else if (tid < 768) {
            int o = (tid - 384) << 1;
            float v0 = bhh[o], v1 = bhh[o + 1];
#pragma unroll
            for (int s = 0; s < 4; ++s) {
                v0 += __hip_atomic_load(&mygg[s * 1536 + 768 + o],     __ATOMIC_RELAXED, __HIP_MEMORY_SCOPE_AGENT);
                v1 += __hip_atomic_load(&mygg[s * 1536 + 768 + o + 1], __ATOMIC_RELAXED, __HIP_MEMORY_SCOPE_AGENT);
            }
            gh[o] = v0; gh[o + 1] = v1;
        }
        __syncthreads();

        // ---- gates + h update ; assemble xo=[h,ctx,cv] ----
        if (tid < 256) {
            float r = sig_fast(gi[tid] + gh[tid]);
            float z = sig_fast(gi[256 + tid] + gh[256 + tid]);
            float n = tanh_fast(fmaf(r, gh[512 + tid], gi[512 + tid]));
            float hold = hv[tid];
            float hn = (1.0f - z) * n + z * hold;
            hv[tid] = hn;
            hbs[tid] = hn + cov_b[tid];
            xo[tid] = hn;
        } else if (tid < KX_) {
            xo[tid] = xv[tid];
        }
        __syncthreads();

        // ---- output layer: this block's class chunk only ----
        {
            int cc = tid & 31;
            int ch = tid >> 5;
            int k0 = ch * 20;
            int k1 = k0 + 20; if (k1 > KX_) k1 = KX_;
            float a = 0.0f;
            for (int k = k0; k < k1; ++k)
                a = fmaf(xo[k], bf2f(WoutT[(size_t)k * 128 + cbase + cc]), a);
            outp[(ch << 5) + cc] = a;
        }
        __syncthreads();
        if (tid < ccnt) {
            float s3 = outb[cbase + tid];
#pragma unroll
            for (int i = 0; i < 32; ++i) s3 += outp[(i << 5) + tid];
            OUT[((size_t)b * T_ + t) * Cc_ + cbase + tid] = s3;
        }
        __syncthreads();
    }
}

// ---------------- launch ----------------
extern "C" void kernel_launch(void* const* d_in, const int* in_sizes, int n_in,
                              void* d_out, int out_size, void* d_ws, size_t ws_size,
                              hipStream_t stream) {
    const float* fm      = (const float*)d_in[0];
    const float* cvv     = (const float*)d_in[1];
    const int*   tgt     = (const int*)d_in[2];
    const float* conv_w  = (const float*)d_in[3];
    const float* conv_b  = (const float*)d_in[4];
    const float* emb     = (const float*)d_in[5];
    const float* wih     = (const float*)d_in[6];
    const float* whh     = (const float*)d_in[7];
    const float* bih     = (const float*)d_in[8];
    const float* bhh     = (const float*)d_in[9];
    const float* attn_w  = (const float*)d_in[10];
    const float* attn_b  = (const float*)d_in[11];
    const float* attn_v  = (const float*)d_in[12];
    const float* attn_vb = (const float*)d_in[13];
    const float* cov_w   = (const float*)d_in[14];
    const float* cov_b   = (const float*)d_in[15];
    const float* outw    = (const float*)d_in[16];
    const float* outb    = (const float*)d_in[17];
    float* OUT = (float*)d_out;
    char* ws = (char*)d_ws;

    unsigned short* F     = (unsigned short*)(ws);                 // 67,108,864
    unsigned short* Wc    = (unsigned short*)(ws + 67108864);      //  1,048,576
    float*          biasC = (float*)(ws + 68157440);               //  2,097,152
    float*          PE    = (float*)(ws + 70254592);               //  2,097,152
    unsigned short* WihT  = (unsigned short*)(ws + 72351744);      //    956,928
    unsigned short* WhhT  = (unsigned short*)(ws + 73308672);      //    393,216
    unsigned short* WoutT = (unsigned short*)(ws + 73701888);      //    159,488

    // decoder barrier/exchange scratch: reuses the biasC+PE region, which is
    // dead after gemm_feats completes (re-written by prep kernels next launch)
    int*   bar  = (int*)(ws + 68157440);                           //  4 KB (64 batches x 16-int stride)
    float* gsum = (float*)(ws + 68161536);                         //  2 KB [b][par][4]
    float* gctx = (float*)(ws + 68165632);                         //  512 KB [b][par][4][256]
    float* ggih = (float*)(ws + 68689920);                         //  3 MB [b][par][4][1536]

    pe_kernel<<<2048, 256, 0, stream>>>(PE);
    wc_kernel<<<dim3(4, 512), 256, 0, stream>>>(conv_w, attn_w, Wc);
    biasf_kernel<<<1024, 256, 0, stream>>>(conv_b, PE, biasC);
    biasw_kernel<<<dim3(4, 256), 256, 0, stream>>>(conv_b, PE, attn_w, attn_b, biasC);
    wiht_kernel<<<1869, 256, 0, stream>>>(wih, WihT);
    whht_kernel<<<768, 256, 0, stream>>>(whh, WhhT);
    woutt_kernel<<<271, 256, 0, stream>>>(outw, WoutT);
    gemm_feats<<<dim3(512, 4), 256, 0, stream>>>(fm, Wc, biasC, F);
    zero_kernel<<<4, 256, 0, stream>>>(bar, 1024);
    decoder_kernel<<<256, 1024, 0, stream>>>(F, WihT, WhhT, WoutT,
        cvv, tgt, emb, bih, bhh, attn_v, attn_vb, cov_w, cov_b, outb,
        bar, gsum, gctx, ggih, OUT);
}

// Round 2
// 2857.127 us; speedup vs baseline: 1.9930x; 1.1549x over previous
//
#include <hip/hip_runtime.h>
#include <hip/hip_bf16.h>
#include <cstdint>
#include <cstddef>

#define B_   64
#define CIN  1024
#define L_   1024
#define T_   64
#define Hh_  256
#define Dd_  256
#define Cc_  111
#define NO_  512
#define KX_  623

typedef __attribute__((ext_vector_type(8))) short short8;
typedef __attribute__((ext_vector_type(4))) float floatx4;

__device__ __forceinline__ float bf2f(unsigned short u) {
    union { unsigned int i; float f; } v; v.i = ((unsigned int)u) << 16; return v.f;
}
__device__ __forceinline__ unsigned short f2bf(float f) {
    union { float f; unsigned int i; } v; v.f = f;
    return (unsigned short)((v.i + 0x7fffu + ((v.i >> 16) & 1u)) >> 16);
}
__device__ __forceinline__ float frcp(float x) { return __builtin_amdgcn_rcpf(x); }
__device__ __forceinline__ float tanh_fast(float x) {
    return 1.0f - 2.0f * frcp(1.0f + __expf(2.0f * x));
}
__device__ __forceinline__ float sig_fast(float x) {
    return frcp(1.0f + __expf(-x));
}

// ---------------- prep kernels ----------------

__global__ void pe_kernel(float* __restrict__ PE) {
    int idx = blockIdx.x * 256 + threadIdx.x;
    if (idx >= L_ * NO_) return;
    int l = idx >> 9, j = idx & 511;
    int i2 = j & ~1;
    float div = expf((float)i2 * (-9.210340371976184f / 512.0f));
    float arg = (float)l * div;
    PE[idx] = (j & 1) ? cosf(arg) : sinf(arg);
}

__global__ void wc_kernel(const float* __restrict__ conv_w,
                          const float* __restrict__ attn_w,
                          unsigned short* __restrict__ Wc) {
    int c = blockIdx.x * 256 + threadIdx.x;
    int o = blockIdx.y;
    float v;
    if (o < 256) {
        v = conv_w[(size_t)o * CIN + c];
    } else {
        const float* aw = attn_w + (size_t)(o - 256) * 512;
        float a = 0.0f;
        for (int d = 0; d < 512; ++d)
            a = fmaf(aw[d], conv_w[(size_t)d * CIN + c], a);
        v = a;
    }
    Wc[(size_t)o * CIN + c] = f2bf(v);
}

__global__ void biasf_kernel(const float* __restrict__ conv_b,
                             const float* __restrict__ PE,
                             float* __restrict__ biasC) {
    int idx = blockIdx.x * 256 + threadIdx.x;
    int l = idx >> 8, j = idx & 255;
    biasC[(size_t)l * NO_ + j] = conv_b[j] + PE[(size_t)l * NO_ + j];
}

__global__ void biasw_kernel(const float* __restrict__ conv_b,
                             const float* __restrict__ PE,
                             const float* __restrict__ attn_w,
                             const float* __restrict__ attn_b,
                             float* __restrict__ biasC) {
    int l = blockIdx.x * 256 + threadIdx.x;
    int h = blockIdx.y;
    const float* aw = attn_w + (size_t)h * 512;
    const float* pe = PE + (size_t)l * NO_;
    float a = 0.0f;
    for (int d = 0; d < 512; ++d)
        a = fmaf(aw[d], conv_b[d] + pe[d], a);
    biasC[(size_t)l * NO_ + 256 + h] = a + attn_b[h];
}

__global__ void wiht_kernel(const float* __restrict__ wih, unsigned short* __restrict__ WihT) {
    int idx = blockIdx.x * 256 + threadIdx.x;
    if (idx >= 768 * KX_) return;
    int o = idx / KX_, k = idx - o * KX_;
    WihT[(size_t)k * 768 + o] = f2bf(wih[idx]);
}
__global__ void whht_kernel(const float* __restrict__ whh, unsigned short* __restrict__ WhhT) {
    int idx = blockIdx.x * 256 + threadIdx.x;
    if (idx >= 768 * 256) return;
    int o = idx >> 8, k = idx & 255;
    WhhT[(size_t)k * 768 + o] = f2bf(whh[idx]);
}
__global__ void woutt_kernel(const float* __restrict__ outw, unsigned short* __restrict__ WoutT) {
    int idx = blockIdx.x * 256 + threadIdx.x;
    if (idx >= Cc_ * KX_) return;
    int c = idx / KX_, k = idx - c * KX_;
    WoutT[(size_t)k * 128 + c] = f2bf(outw[idx]);
}

__global__ void zero_kernel(int* __restrict__ p, int n) {
    int i = blockIdx.x * 256 + threadIdx.x;
    if (i < n) p[i] = 0;
}

// ---------------- fused conv+projection GEMM (unchanged) ----------------
__global__ __launch_bounds__(256) void gemm_feats(
    const float* __restrict__ fm,
    const unsigned short* __restrict__ Wc,
    const float* __restrict__ biasC,
    unsigned short* __restrict__ F) {
    __shared__ __align__(16) unsigned short Als[128 * 40];
    __shared__ __align__(16) unsigned short Bls[128 * 40];
    const int tid  = threadIdx.x;
    const int bx   = blockIdx.x;
    const int bb   = bx >> 3;
    const int l0   = (bx & 7) << 7;
    const int n0   = blockIdx.y << 7;
    const int wid  = tid >> 6;
    const int lane = tid & 63;
    const int m0w  = (wid & 1) << 6;
    const int n0w  = (wid >> 1) << 6;
    const int quad = lane >> 4;
    const int l16  = lane & 15;

    floatx4 acc[4][4];
#pragma unroll
    for (int i = 0; i < 4; ++i)
#pragma unroll
        for (int j = 0; j < 4; ++j)
            acc[i][j] = (floatx4){0.f, 0.f, 0.f, 0.f};

    const int lt    = tid & 127;
    const int chalf = tid >> 7;
    const float* fmb = fm + ((size_t)bb * CIN) * L_ + l0 + lt;
    const int bo = tid >> 2;
    const int bc = (tid & 3) << 3;
    const int swzA = ((lt >> 2) & 3) << 3;

    for (int kk = 0; kk < 32; ++kk) {
        const int c0 = kk << 5;
        __syncthreads();
#pragma unroll
        for (int i = 0; i < 8; ++i) {
            int cc = (chalf + (i << 1)) << 1;
            float v0 = fmb[(size_t)(c0 + cc) * L_];
            float v1 = fmb[(size_t)(c0 + cc + 1) * L_];
            unsigned int pk = (unsigned int)f2bf(v0) | ((unsigned int)f2bf(v1) << 16);
            *(unsigned int*)(&Als[lt * 40 + (cc ^ swzA)]) = pk;
        }
#pragma unroll
        for (int i = 0; i < 2; ++i) {
            int o = bo + (i << 6);
            uint4 w = *(const uint4*)(&Wc[(size_t)(n0 + o) * CIN + c0 + bc]);
            *(uint4*)(&Bls[o * 40 + bc]) = w;
        }
        __syncthreads();
        short8 afr[4], bfr[4];
#pragma unroll
        for (int mf = 0; mf < 4; ++mf) {
            int mm = m0w + (mf << 4) + l16;
            int k0 = (quad << 3) ^ (((mm >> 2) & 3) << 3);
            afr[mf] = *(const short8*)(&Als[mm * 40 + k0]);
        }
#pragma unroll
        for (int nf = 0; nf < 4; ++nf) {
            int nn = n0w + (nf << 4) + l16;
            bfr[nf] = *(const short8*)(&Bls[nn * 40 + (quad << 3)]);
        }
#pragma unroll
        for (int mf = 0; mf < 4; ++mf)
#pragma unroll
            for (int nf = 0; nf < 4; ++nf)
                acc[mf][nf] = __builtin_amdgcn_mfma_f32_16x16x32_bf16(afr[mf], bfr[nf], acc[mf][nf], 0, 0, 0);
    }

#pragma unroll
    for (int mf = 0; mf < 4; ++mf) {
#pragma unroll
        for (int nf = 0; nf < 4; ++nf) {
            int colg = n0 + n0w + (nf << 4) + l16;
#pragma unroll
            for (int r = 0; r < 4; ++r) {
                int lb = l0 + m0w + (mf << 4) + (quad << 2) + r;
                float v = acc[mf][nf][r] + biasC[(size_t)lb * NO_ + colg];
                F[((size_t)bb * L_ + lb) * NO_ + colg] = f2bf(v);
            }
        }
    }
}

// ---------------- decoder: 4 blocks per batch, per-batch global barrier ----------------
// All cross-block data moves through agent-scope (sc1, L2-bypassing) atomics, so the
// barrier needs NO acquire fence / L2 invalidate: relaxed poll keeps L2 warm for the
// step-invariant weights (WihT/WhhT), cutting both poll cost and matvec load latency.

__device__ __forceinline__ void batch_barrier(int* bar, int target, int tid) {
    __syncthreads();
    if (tid == 0) {
        __hip_atomic_fetch_add(bar, 1, __ATOMIC_RELEASE, __HIP_MEMORY_SCOPE_AGENT);
        while (__hip_atomic_load(bar, __ATOMIC_RELAXED, __HIP_MEMORY_SCOPE_AGENT) < target) {
            __builtin_amdgcn_s_sleep(2);
        }
    }
    __syncthreads();
}

__global__ __launch_bounds__(1024, 4) void decoder_kernel(
    const unsigned short* __restrict__ F,
    const unsigned short* __restrict__ WihT,
    const unsigned short* __restrict__ WhhT,
    const unsigned short* __restrict__ WoutT,
    const float* __restrict__ cvv,
    const int* __restrict__ tgt,
    const float* __restrict__ emb,
    const float* __restrict__ bih,
    const float* __restrict__ bhh,
    const float* __restrict__ attn_v,
    const float* __restrict__ attn_vb,
    const float* __restrict__ cov_w,
    const float* __restrict__ cov_b,
    const float* __restrict__ outb,
    int* __restrict__ bar,
    float* __restrict__ gsum,
    float* __restrict__ gctx,
    float* __restrict__ ggih,
    float* __restrict__ OUT) {
    // Wf (attention half of F, cols 256..511 for this block's 256 l's) lives in
    // LDS for the whole decode: 256 x 256 bf16 = 128 KB. Loaded once.
    __shared__ __align__(16) unsigned short Wls[256 * 256];
    __shared__ float sc[256];     // e_l for this block's l-range
    __shared__ float cov[256];    // coverage for this block's l-range
    __shared__ float xv[640];     // [emb(256) | ctx(256) | cv(111)]
    __shared__ float xo[640];     // [h(256) | ctx(256) | cv(111)]
    __shared__ float hv[256];
    __shared__ __align__(16) float hbs[256];
    __shared__ __align__(16) float cwls[256];
    __shared__ __align__(16) float avls[256];
    __shared__ float gi[768];
    __shared__ float gh[768];
    __shared__ float ctxp[2048];
    __shared__ float outp[1024];
    __shared__ float red[32];
    __shared__ int   tok[T_];

    const int tid  = threadIdx.x;
    // XCD-grouping swizzle: dispatch round-robins blockIdx across the 8 XCDs
    // (xcd = bx & 7). Map so all 4 sub-blocks of a batch share one XCD.
    const int bxr  = blockIdx.x;
    const int q_   = bxr >> 3;
    const int sub  = q_ & 3;
    const int b    = (bxr & 7) | ((q_ >> 2) << 3);
    const int l0   = sub << 8;
    const int lane = tid & 63;
    const int wid  = tid >> 6;
    const int l16  = tid & 15;
    const int lg   = tid >> 4;

    int* mybar = bar + b * 16;

    if (tid < 256) {
        cov[tid] = 0.0f; hv[tid] = 0.0f; hbs[tid] = cov_b[tid];
        cwls[tid] = cov_w[tid]; avls[tid] = attn_v[tid];
    }
    if (tid >= 512 && tid < 512 + Cc_) xv[tid] = cvv[b * Cc_ + (tid - 512)];
    if (tid >= KX_ && tid < 640) xo[tid] = 0.0f;   // zero-pad tail for unguarded out-layer
    if (tid < T_) tok[tid] = (tid == 0) ? 1 : tgt[b * T_ + tid - 1];

    const float avb = attn_vb[0];

    // ---- stage Wf (cols 256..511) into LDS: 8192 x 16B chunks, coalesced ----
#pragma unroll
    for (int i = 0; i < 8; ++i) {
        int c   = (i << 10) + tid;
        int row = c >> 5;
        int col = (c & 31) << 3;
        *(uint4*)(&Wls[(row << 8) + col]) =
            *(const uint4*)(F + (((size_t)(b * L_ + l0 + row)) << 9) + Hh_ + col);
    }

    // ---- stage ctx half (cols 0..255) into registers: 32 packed bf16x2 ----
    unsigned int fctx[32];
    {
        const int hp = (tid & 127) << 1;
        const int ch = tid >> 7;
        const unsigned short* fb = F + (((size_t)(b * L_ + l0 + (ch << 5))) << 9) + hp;
#pragma unroll
        for (int i = 0; i < 32; ++i)
            fctx[i] = *(const unsigned int*)(fb + ((size_t)i << 9));
    }

    const int cbase = sub * 28;
    const int ccnt  = (sub == 3) ? 27 : 28;
    const int kg0 = sub * 156;
    const int kg1 = (kg0 + 156 > KX_) ? KX_ : kg0 + 156;
    const int kh0 = sub << 6;

    // ---- out-layer weights are per-thread constant: hold in registers forever ----
    unsigned short wout_r[20];
    {
        int cc = tid & 31, ch = tid >> 5, k0 = ch * 20;
#pragma unroll
        for (int i = 0; i < 20; ++i) {
            int k = k0 + i;
            wout_r[i] = (k < KX_) ? WoutT[(size_t)k * 128 + cbase + cc] : (unsigned short)0;
        }
    }

    int nsync = 0;
    __syncthreads();

    // software-pipelined embedding row (token ids all known upfront)
    float ecur = 0.0f;
    if (tid < 256) ecur = emb[(size_t)tok[0] * Dd_ + tid];

    for (int t = 0; t < T_; ++t) {
        const int par = t & 1;
        float* myctx = gctx + (((size_t)b * 2 + par) * 4) * 256;
        float* mysum = gsum + ((size_t)b * 2 + par) * 4;
        float* mygg  = ggih + (((size_t)b * 2 + par) * 4) * 1536;

        // embedded token (prefetched); issue next step's load to hide latency
        if (tid < 256) {
            xv[tid] = ecur;
            if (t + 1 < T_) ecur = emb[(size_t)tok[t + 1] * Dd_ + tid];
        }

        // ---- attention scores for l in [l0, l0+256): 16 lanes per l ----
#pragma unroll
        for (int pass = 0; pass < 4; ++pass) {
            int ll = (pass << 6) + lg;     // local l
            float covl = cov[ll];
            const unsigned short* wf = &Wls[ll << 8];
            float a = 0.0f;
#pragma unroll
            for (int j = 0; j < 4; ++j) {
                const int hb0 = (j << 6) + (l16 << 2);
                uint2 w = *(const uint2*)(wf + hb0);
                float4 cw4 = *(const float4*)(&cwls[hb0]);
                float4 av4 = *(const float4*)(&avls[hb0]);
                float4 hb4 = *(const float4*)(&hbs[hb0]);
                float g0 = bf2f((unsigned short)(w.x & 0xffffu)) + fmaf(covl, cw4.x, hb4.x);
                float g1 = bf2f((unsigned short)(w.x >> 16))     + fmaf(covl, cw4.y, hb4.y);
                float g2 = bf2f((unsigned short)(w.y & 0xffffu)) + fmaf(covl, cw4.z, hb4.z);
                float g3 = bf2f((unsigned short)(w.y >> 16))     + fmaf(covl, cw4.w, hb4.w);
                a = fmaf(av4.x, tanh_fast(g0), a);
                a = fmaf(av4.y, tanh_fast(g1), a);
                a = fmaf(av4.z, tanh_fast(g2), a);
                a = fmaf(av4.w, tanh_fast(g3), a);
            }
            a += __shfl_xor(a, 1);
            a += __shfl_xor(a, 2);
            a += __shfl_xor(a, 4);
            a += __shfl_xor(a, 8);
            if (l16 == 0) sc[ll] = __expf(a + avb);   // scores are O(1): no max-sub needed
        }
        __syncthreads();

        // ---- local exp-sum (256 values -> red[0..3]) ----
        if (tid < 256) {
            float e = sc[tid];
#pragma unroll
            for (int off = 1; off < 64; off <<= 1) e += __shfl_xor(e, off);
            if (lane == 0) red[wid] = e;
        }

        // ---- partial (unnormalized) context over local l-range: pure VALU ----
        {
            int hp = (tid & 127) << 1;
            int ch = tid >> 7;
            float c0a = 0.0f, c1a = 0.0f;
#pragma unroll
            for (int i = 0; i < 32; ++i) {
                float al = sc[(ch << 5) + i];
                unsigned int w = fctx[i];
                c0a = fmaf(al, bf2f((unsigned short)(w & 0xffffu)), c0a);
                c1a = fmaf(al, bf2f((unsigned short)(w >> 16)), c1a);
            }
            ctxp[(ch << 8) + hp]     = c0a;
            ctxp[(ch << 8) + hp + 1] = c1a;
        }
        __syncthreads();

        // ---- publish partials ----
        if (tid < 256) {
            float s2 = 0.0f;
#pragma unroll
            for (int i = 0; i < 8; ++i) s2 += ctxp[(i << 8) + tid];
            __hip_atomic_store(&myctx[sub * 256 + tid], s2, __ATOMIC_RELAXED, __HIP_MEMORY_SCOPE_AGENT);
        } else if (tid == 256) {
            float ss = red[0] + red[1] + red[2] + red[3];
            __hip_atomic_store(&mysum[sub], ss, __ATOMIC_RELAXED, __HIP_MEMORY_SCOPE_AGENT);
        }

        ++nsync;
        batch_barrier(mybar, 4 * nsync, tid);

        // ---- assemble full context + 1/S ----
        float s2 = 0.0f;
        if (tid < 256) {
#pragma unroll
            for (int s = 0; s < 4; ++s)
                s2 += __hip_atomic_load(&myctx[s * 256 + tid], __ATOMIC_RELAXED, __HIP_MEMORY_SCOPE_AGENT);
        } else if (tid == 256) {
            float S = 0.0f;
#pragma unroll
            for (int s = 0; s < 4; ++s)
                S += __hip_atomic_load(&mysum[s], __ATOMIC_RELAXED, __HIP_MEMORY_SCOPE_AGENT);
            red[16] = frcp(S);
        }
        __syncthreads();
        float rS = red[16];
        if (tid < 256) {
            xv[256 + tid] = s2 * rS;
            cov[tid] += sc[tid] * rS;
        }
        __syncthreads();

        // ---- GRU partial matvecs (K-split 4-way) ----
        if (tid < 384) {
            int o = tid << 1;
            float a0 = 0.0f, a1 = 0.0f;
            const unsigned short* wp = WihT + (size_t)kg0 * 768 + o;
#pragma unroll 4
            for (int k = kg0; k < kg1; ++k) {
                float x = xv[k];
                unsigned int w = *(const unsigned int*)wp;
                wp += 768;
                a0 = fmaf(x, bf2f((unsigned short)(w & 0xffffu)), a0);
                a1 = fmaf(x, bf2f((unsigned short)(w >> 16)), a1);
            }
            __hip_atomic_store(&mygg[sub * 1536 + o],     a0, __ATOMIC_RELAXED, __HIP_MEMORY_SCOPE_AGENT);
            __hip_atomic_store(&mygg[sub * 1536 + o + 1], a1, __ATOMIC_RELAXED, __HIP_MEMORY_SCOPE_AGENT);
        } else if (tid < 768) {
            int o = (tid - 384) << 1;
            float a0 = 0.0f, a1 = 0.0f;
            const unsigned short* wp = WhhT + (size_t)kh0 * 768 + o;
#pragma unroll 4
            for (int k = kh0; k < kh0 + 64; ++k) {
                float x = hv[k];
                unsigned int w = *(const unsigned int*)wp;
                wp += 768;
                a0 = fmaf(x, bf2f((unsigned short)(w & 0xffffu)), a0);
                a1 = fmaf(x, bf2f((unsigned short)(w >> 16)), a1);
            }
            __hip_atomic_store(&mygg[sub * 1536 + 768 + o],     a0, __ATOMIC_RELAXED, __HIP_MEMORY_SCOPE_AGENT);
            __hip_atomic_store(&mygg[sub * 1536 + 768 + o + 1], a1, __ATOMIC_RELAXED, __HIP_MEMORY_SCOPE_AGENT);
        }

        ++nsync;
        batch_barrier(mybar, 4 * nsync, tid);

        // ---- reduce gi/gh (deterministic order -> identical h in all replicas) ----
        if (tid < 384) {
            int o = tid << 1;
            float v0 = bih[o], v1 = bih[o + 1];
#pragma unroll
            for (int s = 0; s < 4; ++s) {
                v0 += __hip_atomic_load(&mygg[s * 1536 + o],     __ATOMIC_RELAXED, __HIP_MEMORY_SCOPE_AGENT);
                v1 += __hip_atomic_load(&mygg[s * 1536 + o + 1], __ATOMIC_RELAXED, __HIP_MEMORY_SCOPE_AGENT);
            }
            gi[o] = v0; gi[o + 1] = v1;
        } else if (tid < 768) {
            int o = (tid - 384) << 1;
            float v0 = bhh[o], v1 = bhh[o + 1];
#pragma unroll
            for (int s = 0; s < 4; ++s) {
                v0 += __hip_atomic_load(&mygg[s * 1536 + 768 + o],     __ATOMIC_RELAXED, __HIP_MEMORY_SCOPE_AGENT);
                v1 += __hip_atomic_load(&mygg[s * 1536 + 768 + o + 1], __ATOMIC_RELAXED, __HIP_MEMORY_SCOPE_AGENT);
            }
            gh[o] = v0; gh[o + 1] = v1;
        }
        __syncthreads();

        // ---- gates + h update ; assemble xo=[h,ctx,cv] ----
        if (tid < 256) {
            float r = sig_fast(gi[tid] + gh[tid]);
            float z = sig_fast(gi[256 + tid] + gh[256 + tid]);
            float n = tanh_fast(fmaf(r, gh[512 + tid], gi[512 + tid]));
            float hold = hv[tid];
            float hn = (1.0f - z) * n + z * hold;
            hv[tid] = hn;
            hbs[tid] = hn + cov_b[tid];
            xo[tid] = hn;
        } else if (tid < KX_) {
            xo[tid] = xv[tid];
        }
        __syncthreads();

        // ---- output layer: this block's class chunk, weights from registers ----
        {
            int ch = tid >> 5;
            int k0 = ch * 20;
            float a = 0.0f;
#pragma unroll
            for (int i = 0; i < 20; ++i)
                a = fmaf(xo[k0 + i], bf2f(wout_r[i]), a);
            outp[tid] = a;
        }
        __syncthreads();
        if (tid < ccnt) {
            float s3 = outb[cbase + tid];
#pragma unroll
            for (int i = 0; i < 32; ++i) s3 += outp[(i << 5) + tid];
            __builtin_nontemporal_store(s3, &OUT[((size_t)b * T_ + t) * Cc_ + cbase + tid]);
        }
        __syncthreads();
    }
}

// ---------------- launch ----------------
extern "C" void kernel_launch(void* const* d_in, const int* in_sizes, int n_in,
                              void* d_out, int out_size, void* d_ws, size_t ws_size,
                              hipStream_t stream) {
    const float* fm      = (const float*)d_in[0];
    const float* cvv     = (const float*)d_in[1];
    const int*   tgt     = (const int*)d_in[2];
    const float* conv_w  = (const float*)d_in[3];
    const float* conv_b  = (const float*)d_in[4];
    const float* emb     = (const float*)d_in[5];
    const float* wih     = (const float*)d_in[6];
    const float* whh     = (const float*)d_in[7];
    const float* bih     = (const float*)d_in[8];
    const float* bhh     = (const float*)d_in[9];
    const float* attn_w  = (const float*)d_in[10];
    const float* attn_b  = (const float*)d_in[11];
    const float* attn_v  = (const float*)d_in[12];
    const float* attn_vb = (const float*)d_in[13];
    const float* cov_w   = (const float*)d_in[14];
    const float* cov_b   = (const float*)d_in[15];
    const float* outw    = (const float*)d_in[16];
    const float* outb    = (const float*)d_in[17];
    float* OUT = (float*)d_out;
    char* ws = (char*)d_ws;

    unsigned short* F     = (unsigned short*)(ws);                 // 67,108,864
    unsigned short* Wc    = (unsigned short*)(ws + 67108864);      //  1,048,576
    float*          biasC = (float*)(ws + 68157440);               //  2,097,152
    float*          PE    = (float*)(ws + 70254592);               //  2,097,152
    unsigned short* WihT  = (unsigned short*)(ws + 72351744);      //    956,928
    unsigned short* WhhT  = (unsigned short*)(ws + 73308672);      //    393,216
    unsigned short* WoutT = (unsigned short*)(ws + 73701888);      //    159,488

    // decoder barrier/exchange scratch: reuses the biasC+PE region, which is
    // dead after gemm_feats completes (re-written by prep kernels next launch)
    int*   bar  = (int*)(ws + 68157440);                           //  4 KB (64 batches x 16-int stride)
    float* gsum = (float*)(ws + 68161536);                         //  2 KB [b][par][4]
    float* gctx = (float*)(ws + 68165632);                         //  512 KB [b][par][4][256]
    float* ggih = (float*)(ws + 68689920);                         //  3 MB [b][par][4][1536]

    pe_kernel<<<2048, 256, 0, stream>>>(PE);
    wc_kernel<<<dim3(4, 512), 256, 0, stream>>>(conv_w, attn_w, Wc);
    biasf_kernel<<<1024, 256, 0, stream>>>(conv_b, PE, biasC);
    biasw_kernel<<<dim3(4, 256), 256, 0, stream>>>(conv_b, PE, attn_w, attn_b, biasC);
    wiht_kernel<<<1869, 256, 0, stream>>>(wih, WihT);
    whht_kernel<<<768, 256, 0, stream>>>(whh, WhhT);
    woutt_kernel<<<271, 256, 0, stream>>>(outw, WoutT);
    gemm_feats<<<dim3(512, 4), 256, 0, stream>>>(fm, Wc, biasC, F);
    zero_kernel<<<4, 256, 0, stream>>>(bar, 1024);
    decoder_kernel<<<256, 1024, 0, stream>>>(F, WihT, WhhT, WoutT,
        cvv, tgt, emb, bih, bhh, attn_v, attn_vb, cov_w, cov_b, outb,
        bar, gsum, gctx, ggih, OUT);
}

// Round 3
// 2646.563 us; speedup vs baseline: 2.1515x; 1.0796x over previous
//
#include <hip/hip_runtime.h>
#include <hip/hip_bf16.h>
#include <cstdint>
#include <cstddef>

#define B_   64
#define CIN  1024
#define L_   1024
#define T_   64
#define Hh_  256
#define Dd_  256
#define Cc_  111
#define NO_  512
#define KX_  623

typedef __attribute__((ext_vector_type(8))) short short8;
typedef __attribute__((ext_vector_type(4))) float floatx4;

__device__ __forceinline__ float bf2f(unsigned short u) {
    union { unsigned int i; float f; } v; v.i = ((unsigned int)u) << 16; return v.f;
}
__device__ __forceinline__ unsigned short f2bf(float f) {
    union { float f; unsigned int i; } v; v.f = f;
    return (unsigned short)((v.i + 0x7fffu + ((v.i >> 16) & 1u)) >> 16);
}
__device__ __forceinline__ float frcp(float x) { return __builtin_amdgcn_rcpf(x); }
__device__ __forceinline__ float tanh_fast(float x) {
    return 1.0f - 2.0f * frcp(1.0f + __expf(2.0f * x));
}
__device__ __forceinline__ float sig_fast(float x) {
    return frcp(1.0f + __expf(-x));
}

// ---------------- prep kernels ----------------

__global__ void pe_kernel(float* __restrict__ PE) {
    int idx = blockIdx.x * 256 + threadIdx.x;
    if (idx >= L_ * NO_) return;
    int l = idx >> 9, j = idx & 511;
    int i2 = j & ~1;
    float div = expf((float)i2 * (-9.210340371976184f / 512.0f));
    float arg = (float)l * div;
    PE[idx] = (j & 1) ? cosf(arg) : sinf(arg);
}

__global__ void wc_kernel(const float* __restrict__ conv_w,
                          const float* __restrict__ attn_w,
                          unsigned short* __restrict__ Wc) {
    int c = blockIdx.x * 256 + threadIdx.x;
    int o = blockIdx.y;
    float v;
    if (o < 256) {
        v = conv_w[(size_t)o * CIN + c];
    } else {
        const float* aw = attn_w + (size_t)(o - 256) * 512;
        float a = 0.0f;
        for (int d = 0; d < 512; ++d)
            a = fmaf(aw[d], conv_w[(size_t)d * CIN + c], a);
        v = a;
    }
    Wc[(size_t)o * CIN + c] = f2bf(v);
}

__global__ void biasf_kernel(const float* __restrict__ conv_b,
                             const float* __restrict__ PE,
                             float* __restrict__ biasC) {
    int idx = blockIdx.x * 256 + threadIdx.x;
    int l = idx >> 8, j = idx & 255;
    biasC[(size_t)l * NO_ + j] = conv_b[j] + PE[(size_t)l * NO_ + j];
}

__global__ void biasw_kernel(const float* __restrict__ conv_b,
                             const float* __restrict__ PE,
                             const float* __restrict__ attn_w,
                             const float* __restrict__ attn_b,
                             float* __restrict__ biasC) {
    int l = blockIdx.x * 256 + threadIdx.x;
    int h = blockIdx.y;
    const float* aw = attn_w + (size_t)h * 512;
    const float* pe = PE + (size_t)l * NO_;
    float a = 0.0f;
    for (int d = 0; d < 512; ++d)
        a = fmaf(aw[d], conv_b[d] + pe[d], a);
    biasC[(size_t)l * NO_ + 256 + h] = a + attn_b[h];
}

__global__ void wiht_kernel(const float* __restrict__ wih, unsigned short* __restrict__ WihT) {
    int idx = blockIdx.x * 256 + threadIdx.x;
    if (idx >= 768 * KX_) return;
    int o = idx / KX_, k = idx - o * KX_;
    WihT[(size_t)k * 768 + o] = f2bf(wih[idx]);
}
__global__ void whht_kernel(const float* __restrict__ whh, unsigned short* __restrict__ WhhT) {
    int idx = blockIdx.x * 256 + threadIdx.x;
    if (idx >= 768 * 256) return;
    int o = idx >> 8, k = idx & 255;
    WhhT[(size_t)k * 768 + o] = f2bf(whh[idx]);
}
__global__ void woutt_kernel(const float* __restrict__ outw, unsigned short* __restrict__ WoutT) {
    int idx = blockIdx.x * 256 + threadIdx.x;
    if (idx >= Cc_ * KX_) return;
    int c = idx / KX_, k = idx - c * KX_;
    WoutT[(size_t)k * 128 + c] = f2bf(outw[idx]);
}

__global__ void zero_kernel(int* __restrict__ p, int n) {
    int i = blockIdx.x * 256 + threadIdx.x;
    if (i < n) p[i] = 0;
}

// ---------------- fused conv+projection GEMM (unchanged) ----------------
__global__ __launch_bounds__(256) void gemm_feats(
    const float* __restrict__ fm,
    const unsigned short* __restrict__ Wc,
    const float* __restrict__ biasC,
    unsigned short* __restrict__ F) {
    __shared__ __align__(16) unsigned short Als[128 * 40];
    __shared__ __align__(16) unsigned short Bls[128 * 40];
    const int tid  = threadIdx.x;
    const int bx   = blockIdx.x;
    const int bb   = bx >> 3;
    const int l0   = (bx & 7) << 7;
    const int n0   = blockIdx.y << 7;
    const int wid  = tid >> 6;
    const int lane = tid & 63;
    const int m0w  = (wid & 1) << 6;
    const int n0w  = (wid >> 1) << 6;
    const int quad = lane >> 4;
    const int l16  = lane & 15;

    floatx4 acc[4][4];
#pragma unroll
    for (int i = 0; i < 4; ++i)
#pragma unroll
        for (int j = 0; j < 4; ++j)
            acc[i][j] = (floatx4){0.f, 0.f, 0.f, 0.f};

    const int lt    = tid & 127;
    const int chalf = tid >> 7;
    const float* fmb = fm + ((size_t)bb * CIN) * L_ + l0 + lt;
    const int bo = tid >> 2;
    const int bc = (tid & 3) << 3;
    const int swzA = ((lt >> 2) & 3) << 3;

    for (int kk = 0; kk < 32; ++kk) {
        const int c0 = kk << 5;
        __syncthreads();
#pragma unroll
        for (int i = 0; i < 8; ++i) {
            int cc = (chalf + (i << 1)) << 1;
            float v0 = fmb[(size_t)(c0 + cc) * L_];
            float v1 = fmb[(size_t)(c0 + cc + 1) * L_];
            unsigned int pk = (unsigned int)f2bf(v0) | ((unsigned int)f2bf(v1) << 16);
            *(unsigned int*)(&Als[lt * 40 + (cc ^ swzA)]) = pk;
        }
#pragma unroll
        for (int i = 0; i < 2; ++i) {
            int o = bo + (i << 6);
            uint4 w = *(const uint4*)(&Wc[(size_t)(n0 + o) * CIN + c0 + bc]);
            *(uint4*)(&Bls[o * 40 + bc]) = w;
        }
        __syncthreads();
        short8 afr[4], bfr[4];
#pragma unroll
        for (int mf = 0; mf < 4; ++mf) {
            int mm = m0w + (mf << 4) + l16;
            int k0 = (quad << 3) ^ (((mm >> 2) & 3) << 3);
            afr[mf] = *(const short8*)(&Als[mm * 40 + k0]);
        }
#pragma unroll
        for (int nf = 0; nf < 4; ++nf) {
            int nn = n0w + (nf << 4) + l16;
            bfr[nf] = *(const short8*)(&Bls[nn * 40 + (quad << 3)]);
        }
#pragma unroll
        for (int mf = 0; mf < 4; ++mf)
#pragma unroll
            for (int nf = 0; nf < 4; ++nf)
                acc[mf][nf] = __builtin_amdgcn_mfma_f32_16x16x32_bf16(afr[mf], bfr[nf], acc[mf][nf], 0, 0, 0);
    }

#pragma unroll
    for (int mf = 0; mf < 4; ++mf) {
#pragma unroll
        for (int nf = 0; nf < 4; ++nf) {
            int colg = n0 + n0w + (nf << 4) + l16;
#pragma unroll
            for (int r = 0; r < 4; ++r) {
                int lb = l0 + m0w + (mf << 4) + (quad << 2) + r;
                float v = acc[mf][nf][r] + biasC[(size_t)lb * NO_ + colg];
                F[((size_t)bb * L_ + lb) * NO_ + colg] = f2bf(v);
            }
        }
    }
}

// ---------------- decoder: 4 blocks per batch, per-batch global barrier ----------------
// All cross-block data moves through agent-scope (sc1, coherent-point) atomics.
// The leading __syncthreads() drains each wave's vmcnt before any wave passes
// (compiler emits s_waitcnt vmcnt(0) before s_barrier), so all published data has
// REACHED the coherent point before tid0 increments the counter. Hence the RMW can
// be RELAXED: no buffer_wbl2 (release) and no buffer_inv (acquire) — the L2 stays
// warm and no serial L2 walks sit on the critical path.

__device__ __forceinline__ void batch_barrier(int* bar, int target, int tid) {
    __syncthreads();
    if (tid == 0) {
        int old = __hip_atomic_fetch_add(bar, 1, __ATOMIC_RELAXED, __HIP_MEMORY_SCOPE_AGENT);
        if (old < target - 1) {   // last arriver (the critical block) skips polling entirely
            while (__hip_atomic_load(bar, __ATOMIC_RELAXED, __HIP_MEMORY_SCOPE_AGENT) < target) {
                __builtin_amdgcn_s_sleep(2);
            }
        }
    }
    __syncthreads();
}

__global__ __launch_bounds__(1024, 4) void decoder_kernel(
    const unsigned short* __restrict__ F,
    const unsigned short* __restrict__ WihT,
    const unsigned short* __restrict__ WhhT,
    const unsigned short* __restrict__ WoutT,
    const float* __restrict__ cvv,
    const int* __restrict__ tgt,
    const float* __restrict__ emb,
    const float* __restrict__ bih,
    const float* __restrict__ bhh,
    const float* __restrict__ attn_v,
    const float* __restrict__ attn_vb,
    const float* __restrict__ cov_w,
    const float* __restrict__ cov_b,
    const float* __restrict__ outb,
    int* __restrict__ bar,
    float* __restrict__ gsum,
    float* __restrict__ gctx,
    float* __restrict__ ggih,
    float* __restrict__ OUT) {
    // Wf (attention half of F, cols 256..511 for this block's 256 l's) lives in
    // LDS for the whole decode: 256 x 256 bf16 = 128 KB. Loaded once.
    __shared__ __align__(16) unsigned short Wls[256 * 256];
    __shared__ float sc[256];     // e_l for this block's l-range
    __shared__ float cov[256];    // coverage for this block's l-range
    __shared__ float xv[640];     // [emb(256) | ctx(256) | cv(111)]
    __shared__ float xo[640];     // [h(256) | ctx(256) | cv(111)]
    __shared__ float hv[256];
    __shared__ __align__(16) float hbs[256];
    __shared__ __align__(16) float cwls[256];
    __shared__ __align__(16) float avls[256];
    __shared__ float gi[768];
    __shared__ float gh[768];
    __shared__ float ctxp[2048];
    __shared__ float outp[1024];
    __shared__ float red[32];
    __shared__ int   tok[T_];

    const int tid  = threadIdx.x;
    // XCD-grouping swizzle: dispatch round-robins blockIdx across the 8 XCDs
    // (xcd = bx & 7). Map so all 4 sub-blocks of a batch share one XCD.
    const int bxr  = blockIdx.x;
    const int q_   = bxr >> 3;
    const int sub  = q_ & 3;
    const int b    = (bxr & 7) | ((q_ >> 2) << 3);
    const int l0   = sub << 8;
    const int lane = tid & 63;
    const int wid  = tid >> 6;
    const int l16  = tid & 15;
    const int lg   = tid >> 4;

    int* mybar = bar + b * 16;

    if (tid < 256) {
        cov[tid] = 0.0f; hv[tid] = 0.0f; hbs[tid] = cov_b[tid];
        cwls[tid] = cov_w[tid]; avls[tid] = attn_v[tid];
    }
    if (tid >= 512 && tid < 512 + Cc_) xv[tid] = cvv[b * Cc_ + (tid - 512)];
    if (tid >= KX_ && tid < 640) xo[tid] = 0.0f;   // zero-pad tail for unguarded out-layer
    if (tid < T_) tok[tid] = (tid == 0) ? 1 : tgt[b * T_ + tid - 1];

    const float avb = attn_vb[0];

    // ---- stage Wf (cols 256..511) into LDS: 8192 x 16B chunks, coalesced ----
#pragma unroll
    for (int i = 0; i < 8; ++i) {
        int c   = (i << 10) + tid;
        int row = c >> 5;
        int col = (c & 31) << 3;
        *(uint4*)(&Wls[(row << 8) + col]) =
            *(const uint4*)(F + (((size_t)(b * L_ + l0 + row)) << 9) + Hh_ + col);
    }

    // ---- stage ctx half (cols 0..255) into registers: 32 packed bf16x2 ----
    unsigned int fctx[32];
    {
        const int hp = (tid & 127) << 1;
        const int ch = tid >> 7;
        const unsigned short* fb = F + (((size_t)(b * L_ + l0 + (ch << 5))) << 9) + hp;
#pragma unroll
        for (int i = 0; i < 32; ++i)
            fctx[i] = *(const unsigned int*)(fb + ((size_t)i << 9));
    }

    const int cbase = sub * 28;
    const int ccnt  = (sub == 3) ? 27 : 28;
    const int kg0 = sub * 156;
    const int kg1 = (kg0 + 156 > KX_) ? KX_ : kg0 + 156;
    const int kh0 = sub << 6;

    // ---- out-layer weights are per-thread constant: hold in registers forever ----
    unsigned short wout_r[20];
    {
        int cc = tid & 31, ch = tid >> 5, k0 = ch * 20;
#pragma unroll
        for (int i = 0; i < 20; ++i) {
            int k = k0 + i;
            wout_r[i] = (k < KX_) ? WoutT[(size_t)k * 128 + cbase + cc] : (unsigned short)0;
        }
    }

    int nsync = 0;
    __syncthreads();

    // software-pipelined embedding row (token ids all known upfront)
    float ecur = 0.0f;
    if (tid < 256) ecur = emb[(size_t)tok[0] * Dd_ + tid];

    for (int t = 0; t < T_; ++t) {
        const int par = t & 1;
        float* myctx = gctx + (((size_t)b * 2 + par) * 4) * 256;
        float* mysum = gsum + ((size_t)b * 2 + par) * 4;
        float* mygg  = ggih + (((size_t)b * 2 + par) * 4) * 1536;

        // embedded token (prefetched); issue next step's load to hide latency
        if (tid < 256) {
            xv[tid] = ecur;
            if (t + 1 < T_) ecur = emb[(size_t)tok[t + 1] * Dd_ + tid];
        }

        // ---- attention scores for l in [l0, l0+256): 16 lanes per l ----
#pragma unroll
        for (int pass = 0; pass < 4; ++pass) {
            int ll = (pass << 6) + lg;     // local l
            float covl = cov[ll];
            const unsigned short* wf = &Wls[ll << 8];
            float a = 0.0f;
#pragma unroll
            for (int j = 0; j < 4; ++j) {
                const int hb0 = (j << 6) + (l16 << 2);
                uint2 w = *(const uint2*)(wf + hb0);
                float4 cw4 = *(const float4*)(&cwls[hb0]);
                float4 av4 = *(const float4*)(&avls[hb0]);
                float4 hb4 = *(const float4*)(&hbs[hb0]);
                float g0 = bf2f((unsigned short)(w.x & 0xffffu)) + fmaf(covl, cw4.x, hb4.x);
                float g1 = bf2f((unsigned short)(w.x >> 16))     + fmaf(covl, cw4.y, hb4.y);
                float g2 = bf2f((unsigned short)(w.y & 0xffffu)) + fmaf(covl, cw4.z, hb4.z);
                float g3 = bf2f((unsigned short)(w.y >> 16))     + fmaf(covl, cw4.w, hb4.w);
                a = fmaf(av4.x, tanh_fast(g0), a);
                a = fmaf(av4.y, tanh_fast(g1), a);
                a = fmaf(av4.z, tanh_fast(g2), a);
                a = fmaf(av4.w, tanh_fast(g3), a);
            }
            a += __shfl_xor(a, 1);
            a += __shfl_xor(a, 2);
            a += __shfl_xor(a, 4);
            a += __shfl_xor(a, 8);
            if (l16 == 0) sc[ll] = __expf(a + avb);   // scores are O(1): no max-sub needed
        }
        __syncthreads();

        // ---- local exp-sum (256 values -> red[0..3]) ----
        if (tid < 256) {
            float e = sc[tid];
#pragma unroll
            for (int off = 1; off < 64; off <<= 1) e += __shfl_xor(e, off);
            if (lane == 0) red[wid] = e;
        }

        // ---- partial (unnormalized) context over local l-range: pure VALU ----
        {
            int hp = (tid & 127) << 1;
            int ch = tid >> 7;
            float c0a = 0.0f, c1a = 0.0f;
#pragma unroll
            for (int i = 0; i < 32; ++i) {
                float al = sc[(ch << 5) + i];
                unsigned int w = fctx[i];
                c0a = fmaf(al, bf2f((unsigned short)(w & 0xffffu)), c0a);
                c1a = fmaf(al, bf2f((unsigned short)(w >> 16)), c1a);
            }
            ctxp[(ch << 8) + hp]     = c0a;
            ctxp[(ch << 8) + hp + 1] = c1a;
        }
        __syncthreads();

        // ---- publish partials ----
        if (tid < 256) {
            float s2 = 0.0f;
#pragma unroll
            for (int i = 0; i < 8; ++i) s2 += ctxp[(i << 8) + tid];
            __hip_atomic_store(&myctx[sub * 256 + tid], s2, __ATOMIC_RELAXED, __HIP_MEMORY_SCOPE_AGENT);
        } else if (tid == 256) {
            float ss = red[0] + red[1] + red[2] + red[3];
            __hip_atomic_store(&mysum[sub], ss, __ATOMIC_RELAXED, __HIP_MEMORY_SCOPE_AGENT);
        }

        ++nsync;
        batch_barrier(mybar, 4 * nsync, tid);

        // ---- assemble full context + 1/S ----
        float s2 = 0.0f;
        if (tid < 256) {
#pragma unroll
            for (int s = 0; s < 4; ++s)
                s2 += __hip_atomic_load(&myctx[s * 256 + tid], __ATOMIC_RELAXED, __HIP_MEMORY_SCOPE_AGENT);
        } else if (tid == 256) {
            float S = 0.0f;
#pragma unroll
            for (int s = 0; s < 4; ++s)
                S += __hip_atomic_load(&mysum[s], __ATOMIC_RELAXED, __HIP_MEMORY_SCOPE_AGENT);
            red[16] = frcp(S);
        }
        __syncthreads();
        float rS = red[16];
        if (tid < 256) {
            xv[256 + tid] = s2 * rS;
            cov[tid] += sc[tid] * rS;
        }
        __syncthreads();

        // ---- GRU partial matvecs (K-split 4-way) ----
        if (tid < 384) {
            int o = tid << 1;
            float a0 = 0.0f, a1 = 0.0f;
            const unsigned short* wp = WihT + (size_t)kg0 * 768 + o;
#pragma unroll 4
            for (int k = kg0; k < kg1; ++k) {
                float x = xv[k];
                unsigned int w = *(const unsigned int*)wp;
                wp += 768;
                a0 = fmaf(x, bf2f((unsigned short)(w & 0xffffu)), a0);
                a1 = fmaf(x, bf2f((unsigned short)(w >> 16)), a1);
            }
            __hip_atomic_store(&mygg[sub * 1536 + o],     a0, __ATOMIC_RELAXED, __HIP_MEMORY_SCOPE_AGENT);
            __hip_atomic_store(&mygg[sub * 1536 + o + 1], a1, __ATOMIC_RELAXED, __HIP_MEMORY_SCOPE_AGENT);
        } else if (tid < 768) {
            int o = (tid - 384) << 1;
            float a0 = 0.0f, a1 = 0.0f;
            const unsigned short* wp = WhhT + (size_t)kh0 * 768 + o;
#pragma unroll 4
            for (int k = kh0; k < kh0 + 64; ++k) {
                float x = hv[k];
                unsigned int w = *(const unsigned int*)wp;
                wp += 768;
                a0 = fmaf(x, bf2f((unsigned short)(w & 0xffffu)), a0);
                a1 = fmaf(x, bf2f((unsigned short)(w >> 16)), a1);
            }
            __hip_atomic_store(&mygg[sub * 1536 + 768 + o],     a0, __ATOMIC_RELAXED, __HIP_MEMORY_SCOPE_AGENT);
            __hip_atomic_store(&mygg[sub * 1536 + 768 + o + 1], a1, __ATOMIC_RELAXED, __HIP_MEMORY_SCOPE_AGENT);
        }

        ++nsync;
        batch_barrier(mybar, 4 * nsync, tid);

        // ---- reduce gi/gh (deterministic order -> identical h in all replicas) ----
        if (tid < 384) {
            int o = tid << 1;
            float v0 = bih[o], v1 = bih[o + 1];
#pragma unroll
            for (int s = 0; s < 4; ++s) {
                v0 += __hip_atomic_load(&mygg[s * 1536 + o],     __ATOMIC_RELAXED, __HIP_MEMORY_SCOPE_AGENT);
                v1 += __hip_atomic_load(&mygg[s * 1536 + o + 1], __ATOMIC_RELAXED, __HIP_MEMORY_SCOPE_AGENT);
            }
            gi[o] = v0; gi[o + 1] = v1;
        } else if (tid < 768) {
            int o = (tid - 384) << 1;
            float v0 = bhh[o], v1 = bhh[o + 1];
#pragma unroll
            for (int s = 0; s < 4; ++s) {
                v0 += __hip_atomic_load(&mygg[s * 1536 + 768 + o],     __ATOMIC_RELAXED, __HIP_MEMORY_SCOPE_AGENT);
                v1 += __hip_atomic_load(&mygg[s * 1536 + 768 + o + 1], __ATOMIC_RELAXED, __HIP_MEMORY_SCOPE_AGENT);
            }
            gh[o] = v0; gh[o + 1] = v1;
        }
        __syncthreads();

        // ---- gates + h update ; assemble xo=[h,ctx,cv] ----
        if (tid < 256) {
            float r = sig_fast(gi[tid] + gh[tid]);
            float z = sig_fast(gi[256 + tid] + gh[256 + tid]);
            float n = tanh_fast(fmaf(r, gh[512 + tid], gi[512 + tid]));
            float hold = hv[tid];
            float hn = (1.0f - z) * n + z * hold;
            hv[tid] = hn;
            hbs[tid] = hn + cov_b[tid];
            xo[tid] = hn;
        } else if (tid < KX_) {
            xo[tid] = xv[tid];
        }
        __syncthreads();

        // ---- output layer: this block's class chunk, weights from registers ----
        {
            int ch = tid >> 5;
            int k0 = ch * 20;
            float a = 0.0f;
#pragma unroll
            for (int i = 0; i < 20; ++i)
                a = fmaf(xo[k0 + i], bf2f(wout_r[i]), a);
            outp[tid] = a;
        }
        __syncthreads();
        if (tid < ccnt) {
            float s3 = outb[cbase + tid];
#pragma unroll
            for (int i = 0; i < 32; ++i) s3 += outp[(i << 5) + tid];
            __builtin_nontemporal_store(s3, &OUT[((size_t)b * T_ + t) * Cc_ + cbase + tid]);
        }
        __syncthreads();
    }
}

// ---------------- launch ----------------
extern "C" void kernel_launch(void* const* d_in, const int* in_sizes, int n_in,
                              void* d_out, int out_size, void* d_ws, size_t ws_size,
                              hipStream_t stream) {
    const float* fm      = (const float*)d_in[0];
    const float* cvv     = (const float*)d_in[1];
    const int*   tgt     = (const int*)d_in[2];
    const float* conv_w  = (const float*)d_in[3];
    const float* conv_b  = (const float*)d_in[4];
    const float* emb     = (const float*)d_in[5];
    const float* wih     = (const float*)d_in[6];
    const float* whh     = (const float*)d_in[7];
    const float* bih     = (const float*)d_in[8];
    const float* bhh     = (const float*)d_in[9];
    const float* attn_w  = (const float*)d_in[10];
    const float* attn_b  = (const float*)d_in[11];
    const float* attn_v  = (const float*)d_in[12];
    const float* attn_vb = (const float*)d_in[13];
    const float* cov_w   = (const float*)d_in[14];
    const float* cov_b   = (const float*)d_in[15];
    const float* outw    = (const float*)d_in[16];
    const float* outb    = (const float*)d_in[17];
    float* OUT = (float*)d_out;
    char* ws = (char*)d_ws;

    unsigned short* F     = (unsigned short*)(ws);                 // 67,108,864
    unsigned short* Wc    = (unsigned short*)(ws + 67108864);      //  1,048,576
    float*          biasC = (float*)(ws + 68157440);               //  2,097,152
    float*          PE    = (float*)(ws + 70254592);               //  2,097,152
    unsigned short* WihT  = (unsigned short*)(ws + 72351744);      //    956,928
    unsigned short* WhhT  = (unsigned short*)(ws + 73308672);      //    393,216
    unsigned short* WoutT = (unsigned short*)(ws + 73701888);      //    159,488

    // decoder barrier/exchange scratch: reuses the biasC+PE region, which is
    // dead after gemm_feats completes (re-written by prep kernels next launch)
    int*   bar  = (int*)(ws + 68157440);                           //  4 KB (64 batches x 16-int stride)
    float* gsum = (float*)(ws + 68161536);                         //  2 KB [b][par][4]
    float* gctx = (float*)(ws + 68165632);                         //  512 KB [b][par][4][256]
    float* ggih = (float*)(ws + 68689920);                         //  3 MB [b][par][4][1536]

    pe_kernel<<<2048, 256, 0, stream>>>(PE);
    wc_kernel<<<dim3(4, 512), 256, 0, stream>>>(conv_w, attn_w, Wc);
    biasf_kernel<<<1024, 256, 0, stream>>>(conv_b, PE, biasC);
    biasw_kernel<<<dim3(4, 256), 256, 0, stream>>>(conv_b, PE, attn_w, attn_b, biasC);
    wiht_kernel<<<1869, 256, 0, stream>>>(wih, WihT);
    whht_kernel<<<768, 256, 0, stream>>>(whh, WhhT);
    woutt_kernel<<<271, 256, 0, stream>>>(outw, WoutT);
    gemm_feats<<<dim3(512, 4), 256, 0, stream>>>(fm, Wc, biasC, F);
    zero_kernel<<<4, 256, 0, stream>>>(bar, 1024);
    decoder_kernel<<<256, 1024, 0, stream>>>(F, WihT, WhhT, WoutT,
        cvv, tgt, emb, bih, bhh, attn_v, attn_vb, cov_w, cov_b, outb,
        bar, gsum, gctx, ggih, OUT);
}